// Round 1
// baseline (127.901 us; speedup 1.0000x reference)
//
#include <hip/hip_runtime.h>
#include <math.h>

// Shapes from reference: B=4, N=256, D=128, M=128, C=128
#define BB 4
#define NN 256
#define DD 128
#define MM 128
#define CC 128
#define ROWS (BB * NN)   // 1024

static __device__ __forceinline__ float fast_exp2(float x) {
#if __has_builtin(__builtin_amdgcn_exp2f)
    return __builtin_amdgcn_exp2f(x);
#else
    return __exp2f(x);
#endif
}

static __device__ __forceinline__ float fast_rcp(float x) {
#if __has_builtin(__builtin_amdgcn_rcpf)
    return __builtin_amdgcn_rcpf(x);
#else
    return 1.0f / x;
#endif
}

// silu(x) = x * sigmoid(x) = x / (1 + exp(-x)) ; exp(-x) = 2^(-x*log2(e))
static __device__ __forceinline__ float silu_f(float x) {
    float e = fast_exp2(-1.44269504088896340736f * x);
    return x * fast_rcp(1.0f + e);
}

// Kernel 1: pibias[row][m] = sum_d h[row][d]*W1a[d][m] + b1[m]
//           pj[row][m]     = sum_d h[row][d]*W1b[d][m]
// R rows per block, 128 threads (thread = output column m).
template <int R>
__global__ __launch_bounds__(128) void k_proj(const float* __restrict__ h,
                                              const float* __restrict__ W1a,
                                              const float* __restrict__ W1b,
                                              const float* __restrict__ b1,
                                              float* __restrict__ pibias,
                                              float* __restrict__ pj) {
    __shared__ float sH[R][DD];
    const int m = threadIdx.x;
    const int row0 = blockIdx.x * R;
    #pragma unroll
    for (int r = 0; r < R; ++r)
        sH[r][m] = h[(row0 + r) * DD + m];
    __syncthreads();

    float accA[R], accB[R];
    const float bias = b1[m];
    #pragma unroll
    for (int r = 0; r < R; ++r) { accA[r] = bias; accB[r] = 0.0f; }

    #pragma unroll 4
    for (int d = 0; d < DD; ++d) {
        const float wa = W1a[d * MM + m];
        const float wb = W1b[d * MM + m];
        #pragma unroll
        for (int r = 0; r < R; ++r) {
            const float hv = sH[r][d];
            accA[r] = fmaf(hv, wa, accA[r]);
            accB[r] = fmaf(hv, wb, accB[r]);
        }
    }
    #pragma unroll
    for (int r = 0; r < R; ++r) {
        pibias[(row0 + r) * MM + m] = accA[r];
        pj[(row0 + r) * MM + m]     = accB[r];
    }
}

// Kernel 2 (dominant): per row (b,i):
//   S[row][m] = inv_denom * sum_{j != i} adj[b,i,j] * silu(pibias[row][m] + pj[b,j][m])
//   beta[row] = inv_denom * sum_{j != i} adj[b,i,j]
// Block = 256 threads: m = t&127, j-half = t>>7. adj row staged in LDS; its
// diagonal entry zeroed in LDS so the hot loop is branch-free.
__global__ __launch_bounds__(256) void k_msg(const float* __restrict__ adj,
                                             const float* __restrict__ pibias,
                                             const float* __restrict__ pj,
                                             float* __restrict__ S,
                                             float* __restrict__ beta) {
    __shared__ float sAdj[NN];
    __shared__ float sRed[256];
    const int t = threadIdx.x;
    const int row = blockIdx.x;          // b*N + i
    const int b = row >> 8;
    const int i = row & 255;

    sAdj[t] = adj[row * NN + t];
    __syncthreads();

    // In-block reduction for the full row sum (denominator).
    sRed[t] = sAdj[t];
    __syncthreads();
    for (int s = 128; s > 0; s >>= 1) {
        if (t < s) sRed[t] += sRed[t + s];
        __syncthreads();
    }
    const float A_full = sRed[0];
    const float a_ii = sAdj[i];
    __syncthreads();                 // everyone has read A_full / a_ii
    if (t == 0) sAdj[i] = 0.0f;      // mask the diagonal once, up front
    __syncthreads();

    const float Aex = A_full - a_ii;
    const float inv = 1.0f / fmaxf(A_full, 1.0f);   // uniform; precise div once

    const int m = t & 127;
    const int half = t >> 7;
    const float pim = pibias[row * MM + m];
    const float* __restrict__ pjB = pj + (size_t)(b << 8) * MM;

    float acc = 0.0f;
    #pragma unroll 4
    for (int j = half; j < NN; j += 2) {
        const float w = sAdj[j];               // wave-uniform broadcast
        const float x = pim + pjB[j * MM + m]; // coalesced L2 hit
        acc = fmaf(w, silu_f(x), acc);
    }

    sRed[t] = acc;
    __syncthreads();
    if (t < 128) {
        const float tot = sRed[t] + sRed[t + 128];
        S[row * MM + t] = tot * inv;
    }
    if (t == 0) beta[row] = Aex * inv;
}

// Kernel 3: fused output head, R rows per block, 128 threads (thread = col k):
//   magg = S@W2 + beta*b2 ; t1 = silu(magg@Wc1 + bc1) ; out = t1@Wc2 + bc2
template <int R>
__global__ __launch_bounds__(128) void k_out(const float* __restrict__ S,
                                             const float* __restrict__ beta,
                                             const float* __restrict__ W2,
                                             const float* __restrict__ b2,
                                             const float* __restrict__ Wc1,
                                             const float* __restrict__ bc1,
                                             const float* __restrict__ Wc2,
                                             const float* __restrict__ bc2,
                                             float* __restrict__ out) {
    __shared__ float sIn[R][MM];
    __shared__ float sMid[R][MM];
    const int k = threadIdx.x;
    const int row0 = blockIdx.x * R;

    float bet[R];
    #pragma unroll
    for (int r = 0; r < R; ++r) {
        sIn[r][k] = S[(row0 + r) * MM + k];
        bet[r] = beta[row0 + r];
    }
    __syncthreads();

    // Stage 1: magg = S@W2 + beta*b2
    float acc[R];
    const float bk2v = b2[k];
    #pragma unroll
    for (int r = 0; r < R; ++r) acc[r] = bet[r] * bk2v;
    #pragma unroll 4
    for (int d = 0; d < MM; ++d) {
        const float wv = W2[d * MM + k];
        #pragma unroll
        for (int r = 0; r < R; ++r) acc[r] = fmaf(sIn[r][d], wv, acc[r]);
    }
    #pragma unroll
    for (int r = 0; r < R; ++r) sMid[r][k] = acc[r];   // separate buffer: no hazard
    __syncthreads();

    // Stage 2: t1 = silu(magg@Wc1 + bc1)
    const float bkc1 = bc1[k];
    #pragma unroll
    for (int r = 0; r < R; ++r) acc[r] = bkc1;
    #pragma unroll 4
    for (int d = 0; d < MM; ++d) {
        const float wv = Wc1[d * MM + k];
        #pragma unroll
        for (int r = 0; r < R; ++r) acc[r] = fmaf(sMid[r][d], wv, acc[r]);
    }
    // All sIn reads finished before the sync above; safe to reuse sIn.
    #pragma unroll
    for (int r = 0; r < R; ++r) sIn[r][k] = silu_f(acc[r]);
    __syncthreads();

    // Stage 3: out = t1@Wc2 + bc2
    const float bkc2 = bc2[k];
    #pragma unroll
    for (int r = 0; r < R; ++r) acc[r] = bkc2;
    #pragma unroll 4
    for (int d = 0; d < MM; ++d) {
        const float wv = Wc2[d * CC + k];
        #pragma unroll
        for (int r = 0; r < R; ++r) acc[r] = fmaf(sIn[r][d], wv, acc[r]);
    }
    #pragma unroll
    for (int r = 0; r < R; ++r) out[(row0 + r) * CC + k] = acc[r];
}

extern "C" void kernel_launch(void* const* d_in, const int* in_sizes, int n_in,
                              void* d_out, int out_size, void* d_ws, size_t ws_size,
                              hipStream_t stream) {
    const float* h   = (const float*)d_in[0];
    const float* adj = (const float*)d_in[1];
    const float* W1a = (const float*)d_in[2];
    const float* W1b = (const float*)d_in[3];
    const float* b1  = (const float*)d_in[4];
    const float* W2  = (const float*)d_in[5];
    const float* b2  = (const float*)d_in[6];
    const float* Wc1 = (const float*)d_in[7];
    const float* bc1 = (const float*)d_in[8];
    const float* Wc2 = (const float*)d_in[9];
    const float* bc2 = (const float*)d_in[10];
    float* out = (float*)d_out;

    // Workspace layout (floats): pibias[1024*128] | pj[1024*128] | S[1024*128] | beta[1024]
    float* ws = (float*)d_ws;
    float* pibias = ws;
    float* pj     = ws + (size_t)ROWS * MM;
    float* S      = ws + (size_t)2 * ROWS * MM;
    float* beta   = ws + (size_t)3 * ROWS * MM;

    k_proj<4><<<ROWS / 4, 128, 0, stream>>>(h, W1a, W1b, b1, pibias, pj);
    k_msg<<<ROWS, 256, 0, stream>>>(adj, pibias, pj, S, beta);
    k_out<4><<<ROWS / 4, 128, 0, stream>>>(S, beta, W2, b2, Wc1, bc1, Wc2, bc2, out);
}

// Round 3
// 104.810 us; speedup vs baseline: 1.2203x; 1.2203x over previous
//
#include <hip/hip_runtime.h>
#include <math.h>

// Shapes from reference: B=4, N=256, D=128, M=128, C=128
#define BB 4
#define NN 256
#define DD 128
#define MM 128
#define CC 128
#define ROWS (BB * NN)   // 1024

static __device__ __forceinline__ float fast_exp2(float x) {
#if __has_builtin(__builtin_amdgcn_exp2f)
    return __builtin_amdgcn_exp2f(x);
#else
    return __exp2f(x);
#endif
}

static __device__ __forceinline__ float fast_rcp(float x) {
#if __has_builtin(__builtin_amdgcn_rcpf)
    return __builtin_amdgcn_rcpf(x);
#else
    return 1.0f / x;
#endif
}

// silu(x) = x / (1 + exp(-x)); exp(-x) = 2^(-x*log2(e))
static __device__ __forceinline__ float silu_f(float x) {
    float e = fast_exp2(-1.44269504088896340736f * x);
    return x * fast_rcp(1.0f + e);
}

// ---------------------------------------------------------------------------
// Kernel 1: pibias = h@W1a + b1 ; pj = h@W1b
// 256 threads: m = t&127 (output col), dh = t>>7 (d-half). R=4 rows/block.
// K-split halves the dependent-load chain and doubles waves/CU vs v1.
// ---------------------------------------------------------------------------
template <int R>
__global__ __launch_bounds__(256) void k_proj(const float* __restrict__ h,
                                              const float* __restrict__ W1a,
                                              const float* __restrict__ W1b,
                                              const float* __restrict__ b1,
                                              float* __restrict__ pibias,
                                              float* __restrict__ pj) {
    __shared__ float sH[R * DD];          // 2 KB
    __shared__ float sPA[R][MM];          // partials from dh==1
    __shared__ float sPB[R][MM];
    const int t = threadIdx.x;
    const int m = t & 127;
    const int dh = t >> 7;
    const int row0 = blockIdx.x * R;

    // Stage h rows (R*128 = 512 floats, contiguous, coalesced).
    const float* hbase = h + (size_t)row0 * DD;
    sH[t] = hbase[t];
    sH[t + 256] = hbase[t + 256];
    __syncthreads();

    const int d0 = dh * 64;
    float accA[R], accB[R];
    #pragma unroll
    for (int r = 0; r < R; ++r) { accA[r] = 0.0f; accB[r] = 0.0f; }

    #pragma unroll 8
    for (int d = d0; d < d0 + 64; ++d) {
        const float wa = W1a[d * MM + m];
        const float wb = W1b[d * MM + m];
        #pragma unroll
        for (int r = 0; r < R; ++r) {
            const float hv = sH[r * DD + d];
            accA[r] = fmaf(hv, wa, accA[r]);
            accB[r] = fmaf(hv, wb, accB[r]);
        }
    }

    if (dh == 1) {
        #pragma unroll
        for (int r = 0; r < R; ++r) { sPA[r][m] = accA[r]; sPB[r][m] = accB[r]; }
    }
    __syncthreads();
    if (dh == 0) {
        const float bias = b1[m];
        #pragma unroll
        for (int r = 0; r < R; ++r) {
            pibias[(row0 + r) * MM + m] = accA[r] + sPA[r][m] + bias;
            pj[(row0 + r) * MM + m]     = accB[r] + sPB[r][m];
        }
    }
}

// ---------------------------------------------------------------------------
// Kernel 2 (dominant VALU): 2 rows (same batch, adjacent i) per block.
//   S[row][m]  = inv * sum_{j != i} adj[row][j] * silu(pibias[row][m] + pj[b,j][m])
//   beta[row]  = inv * sum_{j != i} adj[row][j]
// 256 threads: m = t&127, jh = t>>7. pj load shared by both rows (2 fma/load).
// ---------------------------------------------------------------------------
__global__ __launch_bounds__(256) void k_msg(const float* __restrict__ adj,
                                             const float* __restrict__ pibias,
                                             const float* __restrict__ pj,
                                             float* __restrict__ S,
                                             float* __restrict__ beta) {
    __shared__ float sAdj[2][NN];     // 2 KB
    __shared__ float sRed0[256];
    __shared__ float sRed1[256];
    __shared__ float sWred[2][4];

    const int t = threadIdx.x;
    const int pairIdx = blockIdx.x;       // 512 blocks
    const int b = pairIdx >> 7;           // 128 row-pairs per batch
    const int i0 = (pairIdx & 127) * 2;
    const int row0 = b * NN + i0;         // rows row0, row0+1

    // Stage both adj rows (contiguous 512 floats).
    const float* arow = adj + (size_t)row0 * NN;
    sAdj[0][t] = arow[t];
    sAdj[1][t] = arow[t + 256];
    __syncthreads();

    // Row sums via wave shuffle + tiny LDS combine.
    float v0 = sAdj[0][t];
    float v1 = sAdj[1][t];
    #pragma unroll
    for (int off = 32; off > 0; off >>= 1) {
        v0 += __shfl_xor(v0, off, 64);
        v1 += __shfl_xor(v1, off, 64);
    }
    if ((t & 63) == 0) { sWred[0][t >> 6] = v0; sWred[1][t >> 6] = v1; }
    __syncthreads();
    const float A0 = sWred[0][0] + sWred[0][1] + sWred[0][2] + sWred[0][3];
    const float A1 = sWred[1][0] + sWred[1][1] + sWred[1][2] + sWred[1][3];
    const float aii0 = sAdj[0][i0];        // diagonal elems (broadcast reads)
    const float aii1 = sAdj[1][i0 + 1];
    __syncthreads();                       // all reads done before zeroing
    if (t == 0) { sAdj[0][i0] = 0.0f; sAdj[1][i0 + 1] = 0.0f; }
    __syncthreads();

    const float inv0 = 1.0f / fmaxf(A0, 1.0f);
    const float inv1 = 1.0f / fmaxf(A1, 1.0f);

    const int m = t & 127;
    const int jh = t >> 7;
    const float pim0 = pibias[(size_t)row0 * MM + m];
    const float pim1 = pibias[(size_t)(row0 + 1) * MM + m];
    const float* __restrict__ pjB = pj + (size_t)b * NN * MM;

    float acc0 = 0.0f, acc1 = 0.0f;
    #pragma unroll 8
    for (int j = jh; j < NN; j += 2) {
        const float pjv = pjB[j * MM + m];      // coalesced, shared by 2 rows
        const float w0 = sAdj[0][j];            // wave-uniform broadcast
        const float w1 = sAdj[1][j];
        acc0 = fmaf(w0, silu_f(pim0 + pjv), acc0);
        acc1 = fmaf(w1, silu_f(pim1 + pjv), acc1);
    }

    sRed0[t] = acc0;
    sRed1[t] = acc1;
    __syncthreads();
    if (t < 128) {
        S[(size_t)row0 * MM + t] = (sRed0[t] + sRed0[t + 128]) * inv0;
    } else {
        const int k = t - 128;
        S[(size_t)(row0 + 1) * MM + k] = (sRed1[k] + sRed1[k + 128]) * inv1;
    }
    if (t == 0) {
        beta[row0]     = (A0 - aii0) * inv0;
        beta[row0 + 1] = (A1 - aii1) * inv1;
    }
}

// ---------------------------------------------------------------------------
// Kernel 3: fused head. magg = S@W2 + beta*b2 ; t1 = silu(magg@Wc1+bc1) ;
// out = t1@Wc2 + bc2. 256 threads: k = t&127, dh = t>>7; R=4 rows/block.
// ---------------------------------------------------------------------------
__device__ __forceinline__ void stage_dot4(const float* __restrict__ W,
                                           const float sCur[4][MM],
                                           int d0, int k, float acc[4]) {
    #pragma unroll
    for (int r = 0; r < 4; ++r) acc[r] = 0.0f;
    #pragma unroll 8
    for (int d = d0; d < d0 + 64; ++d) {
        const float wv = W[d * MM + k];
        #pragma unroll
        for (int r = 0; r < 4; ++r) acc[r] = fmaf(sCur[r][d], wv, acc[r]);
    }
}

template <int R>
__global__ __launch_bounds__(256) void k_out(const float* __restrict__ S,
                                             const float* __restrict__ beta,
                                             const float* __restrict__ W2,
                                             const float* __restrict__ b2,
                                             const float* __restrict__ Wc1,
                                             const float* __restrict__ bc1,
                                             const float* __restrict__ Wc2,
                                             const float* __restrict__ bc2,
                                             float* __restrict__ out) {
    __shared__ float sA[R][MM];    // stage input / ping
    __shared__ float sB[R][MM];    // pong
    __shared__ float sP[R][MM];    // cross-half partials
    const int t = threadIdx.x;
    const int k = t & 127;
    const int dh = t >> 7;
    const int d0 = dh * 64;
    const int row0 = blockIdx.x * R;

    float bet[R];
    #pragma unroll
    for (int r = 0; r < R; ++r) bet[r] = beta[row0 + r];

    {
        const float* sbase = S + (size_t)row0 * MM;
        ((float*)sA)[t]       = sbase[t];
        ((float*)sA)[t + 256] = sbase[t + 256];
    }
    __syncthreads();

    float acc[R];

    // ---- Stage 1: magg = S@W2 + beta*b2  (sA -> sB)
    stage_dot4(W2, sA, d0, k, acc);
    if (dh == 1) {
        #pragma unroll
        for (int r = 0; r < R; ++r) sP[r][k] = acc[r];
    }
    __syncthreads();
    if (dh == 0) {
        const float b2k = b2[k];
        #pragma unroll
        for (int r = 0; r < R; ++r) sB[r][k] = acc[r] + sP[r][k] + bet[r] * b2k;
    }
    __syncthreads();

    // ---- Stage 2: t1 = silu(magg@Wc1 + bc1)  (sB -> sA)
    stage_dot4(Wc1, sB, d0, k, acc);
    if (dh == 1) {
        #pragma unroll
        for (int r = 0; r < R; ++r) sP[r][k] = acc[r];
    }
    __syncthreads();
    if (dh == 0) {
        const float bc1k = bc1[k];
        #pragma unroll
        for (int r = 0; r < R; ++r) sA[r][k] = silu_f(acc[r] + sP[r][k] + bc1k);
    }
    __syncthreads();

    // ---- Stage 3: out = t1@Wc2 + bc2  (sA -> global)
    stage_dot4(Wc2, sA, d0, k, acc);
    if (dh == 1) {
        #pragma unroll
        for (int r = 0; r < R; ++r) sP[r][k] = acc[r];
    }
    __syncthreads();
    if (dh == 0) {
        const float bc2k = bc2[k];
        #pragma unroll
        for (int r = 0; r < R; ++r)
            out[(size_t)(row0 + r) * CC + k] = acc[r] + sP[r][k] + bc2k;
    }
}

extern "C" void kernel_launch(void* const* d_in, const int* in_sizes, int n_in,
                              void* d_out, int out_size, void* d_ws, size_t ws_size,
                              hipStream_t stream) {
    const float* h   = (const float*)d_in[0];
    const float* adj = (const float*)d_in[1];
    const float* W1a = (const float*)d_in[2];
    const float* W1b = (const float*)d_in[3];
    const float* b1  = (const float*)d_in[4];
    const float* W2  = (const float*)d_in[5];
    const float* b2  = (const float*)d_in[6];
    const float* Wc1 = (const float*)d_in[7];
    const float* bc1 = (const float*)d_in[8];
    const float* Wc2 = (const float*)d_in[9];
    const float* bc2 = (const float*)d_in[10];
    float* out = (float*)d_out;

    // Workspace (floats): pibias[1024*128] | pj[1024*128] | S[1024*128] | beta[1024]
    float* ws = (float*)d_ws;
    float* pibias = ws;
    float* pj     = ws + (size_t)ROWS * MM;
    float* S      = ws + (size_t)2 * ROWS * MM;
    float* beta   = ws + (size_t)3 * ROWS * MM;

    k_proj<4><<<ROWS / 4, 256, 0, stream>>>(h, W1a, W1b, b1, pibias, pj);
    k_msg<<<ROWS / 2, 256, 0, stream>>>(adj, pibias, pj, S, beta);
    k_out<4><<<ROWS / 4, 256, 0, stream>>>(S, beta, W2, b2, Wc1, bc1, Wc2, bc2, out);
}